// Round 12
// baseline (585.974 us; speedup 1.0000x reference)
//
#include <hip/hip_runtime.h>

// Fake-quant (4-bit signed, symmetric) + bit-flip noise + dequant.
// Pure elementwise, 768 MiB traffic. R1/R6/R7/R9: stuck at ~188us, 2.85 TB/s
// HBM-side, VGPR=24 -- every source-level attempt to batch loads in VGPRs
// (unroll, sched_barrier, asm "+v" tie) was re-serialized by the compiler.
//
// R10: force memory-level parallelism with global_load_lds (DMA to LDS, no
// destination VGPRs -> nothing for the register allocator to re-serialize).
// Wave-private double-buffered pipeline: each wave stages its own 8 KB slice
// and consumes only that slice -> NO barriers. Counted s_waitcnt vmcnt(4)
// keeps next tile's 4 loads in flight across compute (never drain to 0).
// Diagnostic: LDS_Block_Size must read 32768; VGPR staying ~24 is expected.
//
// inputs: d_in[0]=x f32[64M], d_in[1]=q_range f32[1], d_in[2]=epsilon i32[64M]

typedef float f32x4 __attribute__((ext_vector_type(4)));
typedef int   i32x4 __attribute__((ext_vector_type(4)));

#define BLOCK   256
#define WAVES   4                 // BLOCK/64
#define PW      2                 // float4 per thread per stream per tile
#define TILE_F4 (BLOCK * PW)      // 512 float4 per tile per stream

__device__ __forceinline__ float qn_elem(float x, int e, float qr,
                                         float step, float inv_step) {
    float xc = fminf(fmaxf(x, -qr), qr);      // symmetric clip
    float xr = rintf(xc * inv_step);          // RNE, matches jnp.round
    xr = fminf(fmaxf(xr, -8.0f), 7.0f);       // clamp to [QN, QP]
    int u    = ((int)xr) & 15;                // int2bin (two's complement)
    int up   = u ^ e;                         // bit flips
    int pert = (up << 28) >> 28;              // bin2int: 4-bit sign extend
    return (float)pert * step;                // dequant
}

__device__ __forceinline__ f32x4 qn_vec4(f32x4 xv, i32x4 ev, float qr,
                                         float step, float inv_step) {
    f32x4 ov;
#pragma unroll
    for (int c = 0; c < 4; ++c)
        ov[c] = qn_elem(xv[c], ev[c], qr, step, inv_step);
    return ov;
}

__global__ __launch_bounds__(BLOCK) void WCAT_quantnoise_kernel(
    const f32x4* __restrict__ x4,
    const i32x4* __restrict__ e4,
    const float* __restrict__ q_range_p,
    f32x4* __restrict__ out4,
    int n4)
{
    // [buf][wave][PW*64] -- wave-private slices, double buffered. 32 KB total.
    __shared__ f32x4 lx[2][WAVES][PW * 64];
    __shared__ i32x4 le[2][WAVES][PW * 64];

    const float qr       = q_range_p[0];
    const float step     = qr * 0.125f;       // qr / 2^(N_BITS-1), exact
    const float inv_step = 8.0f / qr;         // exact for qr = 2^k

    const int tid  = threadIdx.x;
    const int wid  = tid >> 6;                // wave id, uniform per wave
    const int lane = tid & 63;

    const int NT     = n4 / TILE_F4;
    const int stride = gridDim.x;

    int t   = blockIdx.x;
    int buf = 0;

    // prologue: stage tile t into buf 0 (4 DMA issues per wave)
    if (t < NT) {
#pragma unroll
        for (int j = 0; j < PW; ++j) {
            const f32x4* gx = x4 + (size_t)t * TILE_F4 + wid * (PW * 64) + j * 64 + lane;
            const i32x4* ge = e4 + (size_t)t * TILE_F4 + wid * (PW * 64) + j * 64 + lane;
            __builtin_amdgcn_global_load_lds(
                (const __attribute__((address_space(1))) void*)gx,
                (__attribute__((address_space(3))) void*)&lx[0][wid][j * 64], 16, 0, 0);
            __builtin_amdgcn_global_load_lds(
                (const __attribute__((address_space(1))) void*)ge,
                (__attribute__((address_space(3))) void*)&le[0][wid][j * 64], 16, 0, 0);
        }
    }

    for (; t < NT; t += stride) {
        const int tn = t + stride;
        if (tn < NT) {
            const int nb = buf ^ 1;
            // stage NEXT tile first, so its 4 loads fly during compute
#pragma unroll
            for (int j = 0; j < PW; ++j) {
                const f32x4* gx = x4 + (size_t)tn * TILE_F4 + wid * (PW * 64) + j * 64 + lane;
                const i32x4* ge = e4 + (size_t)tn * TILE_F4 + wid * (PW * 64) + j * 64 + lane;
                __builtin_amdgcn_global_load_lds(
                    (const __attribute__((address_space(1))) void*)gx,
                    (__attribute__((address_space(3))) void*)&lx[nb][wid][j * 64], 16, 0, 0);
                __builtin_amdgcn_global_load_lds(
                    (const __attribute__((address_space(1))) void*)ge,
                    (__attribute__((address_space(3))) void*)&le[nb][wid][j * 64], 16, 0, 0);
            }
            // in-order vmcnt: keep the 4 just-issued (next tile) in flight,
            // drain everything older (current tile's loads + prev stores).
            asm volatile("s_waitcnt vmcnt(4)" ::: "memory");
        } else {
            asm volatile("s_waitcnt vmcnt(0)" ::: "memory");   // last tile
        }
        __builtin_amdgcn_sched_barrier(0);    // rule #18: pin LDS reads below wait

#pragma unroll
        for (int j = 0; j < PW; ++j) {
            f32x4 xv = lx[buf][wid][j * 64 + lane];
            i32x4 ev = le[buf][wid][j * 64 + lane];
            out4[(size_t)t * TILE_F4 + wid * (PW * 64) + j * 64 + lane] =
                qn_vec4(xv, ev, qr, step, inv_step);
        }
        buf ^= 1;
    }

    // tail (n4 % TILE_F4) — empty for 8192^2 but keep general
    for (int i = NT * TILE_F4 + blockIdx.x * BLOCK + tid; i < n4;
         i += gridDim.x * BLOCK) {
        out4[i] = qn_vec4(x4[i], e4[i], qr, step, inv_step);
    }
}

extern "C" void kernel_launch(void* const* d_in, const int* in_sizes, int n_in,
                              void* d_out, int out_size, void* d_ws, size_t ws_size,
                              hipStream_t stream) {
    const float* x       = (const float*)d_in[0];
    const float* q_range = (const float*)d_in[1];
    const int*   epsilon = (const int*)d_in[2];
    float*       out     = (float*)d_out;

    const int n  = in_sizes[0];       // 8192*8192
    const int n4 = n / 4;

    const int NT = n4 / TILE_F4;      // 32768 tiles
    int grid = 2048;                  // 16 tiles/block pipeline depth
    if (grid > NT && NT > 0) grid = NT;
    if (NT == 0) grid = 1;            // pure-tail fallback

    WCAT_quantnoise_kernel<<<grid, BLOCK, 0, stream>>>(
        (const f32x4*)x, (const i32x4*)epsilon, q_range, (f32x4*)out, n4);
}